// Round 11
// baseline (252.484 us; speedup 1.0000x reference)
//
#include <hip/hip_runtime.h>

// WindowAttention (Swin-3D) on MI355X / gfx950.
// R25 = R22 (passing, 200.4us) + ONE change: prep-expanded halfword masks
// (mex) applied post-exp via AND, replacing the ~26-VALU/ktp in-loop bitmask
// chain. Completes the R23 bisect (R24 proved the sigma-V block carried
// R23's entire error; mex contributed none). attn P LDS round trip, Vts
// layout, GEMMs, and all other prep branches byte-identical to R22.

#define DIMD 384
#define NHH 12
#define HEADD 32
#define LL 343
#define NWW 64
#define NTOK (NWW * LL)            // 21952
#define MPT 176                    // m tiles (128 each)
#define MP (MPT * 128)             // 22528
#define LP 352                     // L padded to 22*16
#define QT 22
#define SCALE_ 0.17677669529663687f
#define LOG2E_ 1.4426950408889634f
#define NEGBIG_ (-1.0e4f)

typedef _Float16 f16;
typedef _Float16 v8h __attribute__((ext_vector_type(8)));
typedef _Float16 v4h __attribute__((ext_vector_type(4)));
typedef float v4f __attribute__((ext_vector_type(4)));

__device__ __forceinline__ void async_cp16(const void* g, void* l) {
    __builtin_amdgcn_global_load_lds(
        (const __attribute__((address_space(1))) void*)g,
        (__attribute__((address_space(3))) void*)l, 16, 0, 0);
}

__device__ __forceinline__ unsigned int pk2(float a, float b) {
    return __builtin_bit_cast(unsigned int, __builtin_amdgcn_cvt_pkrtz(a, b));
}

// ---- workspace layout (bytes) ----
constexpr size_t HBUF = (size_t)NHH * MP * HEADD * 2;          // per q/k/v
constexpr size_t OFF_Q    = 0;
constexpr size_t OFF_K    = OFF_Q  + HBUF;
constexpr size_t OFF_V    = OFF_K  + HBUF;
constexpr size_t OFF_AO   = OFF_V  + HBUF;                     // f16 [MP][384]; xh then AO
constexpr size_t OFF_BT   = OFF_AO + (size_t)MP * DIMD * 2;    // f32 biasT (NH,88,352,4) *log2e, key-major
constexpr size_t OFF_WT   = OFF_BT + (size_t)NHH * LP * LP * 4;
constexpr size_t OFF_PWT  = OFF_WT + (size_t)3 * DIMD * DIMD * 2;
constexpr size_t OFF_MEX  = OFF_PWT + (size_t)DIMD * DIMD * 2; // uint4 (NW,11,4,352): halfword masks

// attn LDS: Ks [352][32] + Vts [11][32][32] + Ps 8x[16][32]
constexpr int SMEM_ATTN = (LP * 32 + LP * 32 + 8 * 16 * 32) * 2;   // 53248

// ---------------- fused prep (ILP-restructured) ----------------
// branch order: bias(S3Q) -> mask-expand(S4X) -> x-conv(S0Q) -> wt(S1) -> pwt(S2)
#define S3Q (NHH * LP * LP / 4)        // 371712 threads, 4 bias elems each
#define S4X (NWW * 11 * 4 * LP)        // 991232 threads, one uint4 each
#define S0Q (NTOK * DIMD / 8)          // 1053696 threads, 8 f32 each
#define S1  (3 * DIMD * DIMD)          // 442368
#define S2  (DIMD * DIMD)              // 147456
#define B0  (S3Q)
#define B1  (B0 + S4X)
#define B2  (B1 + S0Q)
#define B3  (B2 + S1)
#define SPREP (B3 + S2)

__global__ __launch_bounds__(256) void prep_all(
    const float* __restrict__ x, f16* __restrict__ xh,
    const float* __restrict__ qkv_w, f16* __restrict__ wt,
    const float* __restrict__ proj_w, f16* __restrict__ pwt,
    const float* __restrict__ table, const int* __restrict__ rel, float* __restrict__ btf,
    const int* __restrict__ mask, unsigned int* __restrict__ mex) {
    int t = blockIdx.x * 256 + threadIdx.x;
    if (t < B0) {
        // biasT[h][kq][col][j] = bias(h, query=col, key=kq*4+j)*log2e, pads -> -1e4
        int h = t / (88 * LP);
        int rem = t % (88 * LP);
        int kq = rem / LP, col = rem % LP;
        int idx[4];
        const int* rrow = rel + col * LL + kq * 4;
#pragma unroll
        for (int j = 0; j < 4; ++j) {
            int key = kq * 4 + j;
            idx[j] = (col < LL && key < LL) ? rrow[j] : -1;
        }
        v4f o;
#pragma unroll
        for (int j = 0; j < 4; ++j)
            o[j] = (idx[j] >= 0) ? table[(size_t)idx[j] * NHH + h] * LOG2E_ : NEGBIG_;
        *(v4f*)(btf + ((size_t)(h * 88 + kq) * LP + col) * 4) = o;
    } else if (t < B1) {
        // mex[n][ktp][quad][q] = uint4 halfword masks (0xFFFF=keep, 0=mask)
        // M.x: keys ktp*32+4*quad+{0,1}; M.y: +{2,3}; M.z: +16+{0,1}; M.w: +16+{2,3}
        int e2 = t - B0;
        int q = e2 % LP;
        int r = e2 / LP;
        int quad = r & 3; r >>= 2;
        int ktp = r % 11, n = r / 11;
        unsigned int M0 = 0, M1 = 0, M2 = 0, M3 = 0;
        if (q < LL) {
            const int* mrow = mask + ((size_t)n * LL + q) * LL;
            int ka = ktp * 32 + quad * 4;          // <= 332, +3 <= 335 < 343: safe
            int b0 = mrow[ka], b1 = mrow[ka + 1], b2 = mrow[ka + 2], b3 = mrow[ka + 3];
            int kz = ka + 16;                      // up to 348: guard per key
            int c0 = (kz     < LL) ? mrow[kz]     : 1;
            int c1 = (kz + 1 < LL) ? mrow[kz + 1] : 1;
            int c2 = (kz + 2 < LL) ? mrow[kz + 2] : 1;
            int c3 = (kz + 3 < LL) ? mrow[kz + 3] : 1;
            M0 = (b0 ? 0u : 0xFFFFu) | (b1 ? 0u : 0xFFFF0000u);
            M1 = (b2 ? 0u : 0xFFFFu) | (b3 ? 0u : 0xFFFF0000u);
            M2 = (c0 ? 0u : 0xFFFFu) | (c1 ? 0u : 0xFFFF0000u);
            M3 = (c2 ? 0u : 0xFFFFu) | (c3 ? 0u : 0xFFFF0000u);
        }
        ((uint4*)mex)[e2] = make_uint4(M0, M1, M2, M3);
    } else if (t < B2) {
        // x -> f16, 8 elems/thread, one 16B store
        int e = t - B1;
        const float4* xp = (const float4*)x + (size_t)e * 2;
        float4 va = xp[0], vb = xp[1];
        v8h o;
        o[0] = (f16)va.x; o[1] = (f16)va.y; o[2] = (f16)va.z; o[3] = (f16)va.w;
        o[4] = (f16)vb.x; o[5] = (f16)vb.y; o[6] = (f16)vb.z; o[7] = (f16)vb.w;
        *(v8h*)(xh + (size_t)e * 8) = o;
    } else if (t < B3) {
        int e = t - B2;
        int n = e / DIMD, k = e % DIMD;          // wt[n][k] = qkv_w[k][n]
        wt[e] = (f16)qkv_w[(size_t)k * (3 * DIMD) + n];
    } else if (t < SPREP) {
        int e = t - B3;
        int n = e / DIMD, k = e % DIMD;
        pwt[e] = (f16)proj_w[(size_t)k * DIMD + n];
    }
}

// ---------------- QKV GEMM (128x128, 2-phase dbuf pipeline, XCD swizzle) ----------------
__global__ __launch_bounds__(256) void qkv_gemm(
    const f16* __restrict__ xh, const f16* __restrict__ wt,
    f16* __restrict__ qb, f16* __restrict__ kb, f16* __restrict__ vb) {
    __shared__ f16 ABs[16384];       // 2 bufs x (A 128x32 + B 128x32)
    const int lin = blockIdx.x;
    const int m0 = ((lin / 72) * 8 + (lin & 7)) * 128;
    const int n0 = ((lin >> 3) % 9) * 128;
    const int tid = threadIdx.x;
    const int wave = tid >> 6, lane = tid & 63;
    const int quad = lane >> 4, l15 = lane & 15;
    const int wm = (wave >> 1) * 64, wn = (wave & 1) * 64;
    const int srow = lane >> 2, scol = (lane & 3) * 8;
    const f16* ga0 = xh + (size_t)(m0 + wave * 32 + srow) * DIMD + scol;
    const f16* ga1 = ga0 + (size_t)16 * DIMD;
    const f16* gb0 = wt + (size_t)(n0 + wave * 32 + srow) * DIMD + scol;
    const f16* gb1 = gb0 + (size_t)16 * DIMD;
    {
        f16* la = ABs + wave * 1024;
        async_cp16(ga0, la);
        async_cp16(ga1, la + 512);
        async_cp16(gb0, la + 4096);
        async_cp16(gb1, la + 4096 + 512);
    }
    __syncthreads();
    v4f acc[4][4] = {};
    for (int t = 0; t < 12; ++t) {
        const int cur = (t & 1) << 13;          // 0 / 8192 f16 flip
        if (t < 11) {                            // prefetch next tile: overlaps MFMA below
            const int nk = (t + 1) * 32;
            f16* la = ABs + (cur ^ 8192) + wave * 1024;
            async_cp16(ga0 + nk, la);
            async_cp16(ga1 + nk, la + 512);
            async_cp16(gb0 + nk, la + 4096);
            async_cp16(gb1 + nk, la + 4096 + 512);
        }
        const f16* As = ABs + cur;
        const f16* Bs = As + 4096;
        v8h a[4], b[4];
#pragma unroll
        for (int i = 0; i < 4; ++i) a[i] = *(const v8h*)(As + (wm + i * 16 + l15) * 32 + quad * 8);
#pragma unroll
        for (int j = 0; j < 4; ++j) b[j] = *(const v8h*)(Bs + (wn + j * 16 + l15) * 32 + quad * 8);
#pragma unroll
        for (int i = 0; i < 4; ++i)
#pragma unroll
            for (int j = 0; j < 4; ++j)
                acc[i][j] = __builtin_amdgcn_mfma_f32_16x16x32_f16(a[i], b[j], acc[i][j], 0, 0, 0);
        __syncthreads();                         // single barrier: drains prefetch (vmcnt0) + protects buf reuse
    }
    // epilogue: per-wave private LDS transpose, zero barriers, coalesced 16B stores
    const int t3 = n0 / DIMD;
    f16* dst = (t3 == 0) ? qb : (t3 == 1) ? kb : vb;
    const float sc = (t3 == 0) ? (SCALE_ * LOG2E_) : 1.0f;
    const int nrel = n0 - t3 * DIMD;
    f16* Cw = ABs + wave * (16 * 72);            // [16 rows][72 stride], wave-private
#pragma unroll
    for (int i = 0; i < 4; ++i) {
#pragma unroll
        for (int e = 0; e < 4; ++e)
#pragma unroll
            for (int j = 0; j < 4; ++j)
                Cw[(quad * 4 + e) * 72 + j * 16 + l15] = (f16)(acc[i][j][e] * sc);
        // same-wave DS ordering: no barrier needed
#pragma unroll
        for (int c = 0; c < 2; ++c) {
            int chunk = quad + c * 4;            // 0..7 -> 8-col piece
            int gm = m0 + wm + i * 16 + l15;
            int gcol = nrel + wn + chunk * 8;
            if (gm < NTOK) {
                size_t off = (size_t)(gcol >> 5) * ((size_t)MP * HEADD)
                           + (gcol & 31) + (size_t)gm * HEADD;
                *(v8h*)(dst + off) = *(const v8h*)(Cw + l15 * 72 + chunk * 8);
            }
        }
    }
}

// ---------------- attention (S^T tiles, mex AND-mask, LDS-P, 3 blk/CU) ----------------
__global__ __launch_bounds__(512, 6) void attn_kernel(
    const f16* __restrict__ qb, const f16* __restrict__ kb, const f16* __restrict__ vb,
    const float* __restrict__ biasT, const unsigned int* __restrict__ mex,
    f16* __restrict__ ao) {
    extern __shared__ char smem[];
    f16* Ks  = (f16*)smem;            // [352 keys][32 ch], 16B-block XOR by (key&3)
    f16* Vts = Ks + LP * 32;          // [11 ktp][32 ch][32 keys], key-block XOR by (ch>>3)&3
    f16* Ps  = Vts + LP * 32;         // 8 waves x [16 q][32 keys], block XOR by ((l15>>1)&3)
    const int bid = blockIdx.x;
    // XCD-chunked swizzle: XCD x owns j2 in [96x, 96x+96) -> 1.5 head slices per XCD L2
    const int j2 = (bid & 7) * 96 + (bid >> 3);
    const int n = j2 & 63, h = j2 >> 6;
    const int tid = threadIdx.x, wave = tid >> 6, lane = tid & 63;
    const int quad = lane >> 4, l15 = lane & 15;
    const size_t slice = ((size_t)h * MP + n * LL) * HEADD;
    const f16* qg = qb + slice;
    const f16* kg = kb + slice;
    const f16* vg = vb + slice;
    // K staging: [key][32ch], swizzled 16B blocks, zero-pad keys >= LL
    for (int i = tid; i < LP * 4; i += 512) {
        int row = i >> 2, c8 = i & 3;
        v8h vv = {};
        if (row < LL) vv = *(const v8h*)(kg + (size_t)i * 8);
        *(v8h*)(Ks + row * 32 + ((c8 ^ (row & 3)) << 3)) = vv;
    }
    // V^T staging: [ktp][ch][key32], key-block XOR by (ch>>3)&3
    for (int i = tid; i < LP * 4; i += 512) {
        int key = i >> 2, c8 = i & 3;
        v8h vv = {};
        if (key < LL) vv = *(const v8h*)(vg + (size_t)key * HEADD + c8 * 8);
        int kk = key & 31;
        f16* d = Vts + (key >> 5) * 1024 + ((((kk >> 3) ^ c8) & 3) << 3) + (kk & 7);
#pragma unroll
        for (int j = 0; j < 8; ++j) d[(c8 * 8 + j) * 32] = vv[j];
    }
    __syncthreads();
    f16* Pw = Ps + wave * (16 * 32);
    const float* bh = biasT + (size_t)h * LP * LP;     // [88 key-quads][352 q][4]
    const v8h ones = {(f16)1.f, (f16)1.f, (f16)1.f, (f16)1.f,
                      (f16)1.f, (f16)1.f, (f16)1.f, (f16)1.f};
    const int pswz = (l15 >> 1) & 3;
    const int kswz = (quad ^ (l15 & 3)) << 3;
    const int xw = (l15 >> 3) & 1;
    for (int qt = wave; qt < QT; qt += 8) {
        const int q = qt * 16 + l15;
        v8h af = *(const v8h*)(qg + (size_t)q * HEADD + quad * 8);      // Q[q][ch]
        const float* bq = bh + (size_t)q * 4;
        const uint4* mexq = (const uint4*)mex + (size_t)n * 44 * LP + (size_t)quad * LP + q;
        v4f cinN[2];
        cinN[0] = *(const v4f*)(bq + (size_t)(quad) * (LP * 4));
        cinN[1] = *(const v4f*)(bq + (size_t)(4 + quad) * (LP * 4));
        uint4 MN = mexq[0];
        v4f o0 = {}, o1 = {}, o2 = {};
#pragma unroll
        for (int ktp = 0; ktp < 11; ++ktp) {
            v4f cin0 = cinN[0], cin1 = cinN[1];
            uint4 M = MN;
            if (ktp < 10) {   // depth-1 prefetch: overlaps this tile's exp/PV
                cinN[0] = *(const v4f*)(bq + (size_t)((ktp + 1) * 8 + quad) * (LP * 4));
                cinN[1] = *(const v4f*)(bq + (size_t)((ktp + 1) * 8 + 4 + quad) * (LP * 4));
                MN = mexq[(size_t)(ktp + 1) * (4 * LP)];
            }
            v8h bf0 = *(const v8h*)(Ks + (ktp * 32 + l15) * 32 + kswz);
            v8h bf1 = *(const v8h*)(Ks + (ktp * 32 + 16 + l15) * 32 + kswz);
            // S^T tile: rows = keys (quad*4+e), cols = queries (l15); C-init = bias
            v4f s0 = __builtin_amdgcn_mfma_f32_16x16x32_f16(bf0, af, cin0, 0, 0, 0);
            v4f s1 = __builtin_amdgcn_mfma_f32_16x16x32_f16(bf1, af, cin1, 0, 0, 0);
            unsigned int u0 = pk2(__builtin_amdgcn_exp2f(s0[0]), __builtin_amdgcn_exp2f(s0[1]));
            unsigned int u1 = pk2(__builtin_amdgcn_exp2f(s0[2]), __builtin_amdgcn_exp2f(s0[3]));
            unsigned int u2 = pk2(__builtin_amdgcn_exp2f(s1[0]), __builtin_amdgcn_exp2f(s1[1]));
            unsigned int u3 = pk2(__builtin_amdgcn_exp2f(s1[2]), __builtin_amdgcn_exp2f(s1[3]));
            // mask post-exp: AND halfwords to zero (equiv. to exp(-1e4) ~ 0)
            u0 &= M.x; u1 &= M.y; u2 &= M.z; u3 &= M.w;
            // P[q=l15][key 0..31]: logical block b = half*2 + (quad>>1), XOR pswz
            // b64 stores: 8B contiguous (keys quad*4..+3), bank-uniform (4 dw/bank)
            f16* pr = Pw + l15 * 32 + (quad & 1) * 4;
            *(uint2*)(pr + ((((quad >> 1) + 0) ^ pswz) << 3)) = make_uint2(u0, u1);
            *(uint2*)(pr + ((((quad >> 1) + 2) ^ pswz) << 3)) = make_uint2(u2, u3);
            v8h a = *(const v8h*)(Pw + l15 * 32 + ((quad ^ pswz) << 3));
            const f16* vt = Vts + ktp * 1024;
            v8h w0 = *(const v8h*)(vt + l15 * 32 + ((quad ^ xw) << 3));            // ch 0..15
            v8h w1 = *(const v8h*)(vt + (16 + l15) * 32 + ((quad ^ 2 ^ xw) << 3)); // ch 16..31
            // O^T: rows = ch (quad*4+e), cols = queries (l15)
            o0 = __builtin_amdgcn_mfma_f32_16x16x32_f16(w0, a, o0, 0, 0, 0);
            o1 = __builtin_amdgcn_mfma_f32_16x16x32_f16(w1, a, o1, 0, 0, 0);
            o2 = __builtin_amdgcn_mfma_f32_16x16x32_f16(ones, a, o2, 0, 0, 0);  // rsum[q]
        }
        if (q < LL) {
            float inv = 1.0f / o2[0];          // rsum for this lane's query, uniform in e
            f16* orow = ao + ((size_t)(n * LL + q)) * DIMD + h * HEADD + quad * 4;
            v4h w0, w1;
#pragma unroll
            for (int e = 0; e < 4; ++e) {
                w0[e] = (f16)(o0[e] * inv);
                w1[e] = (f16)(o1[e] * inv);
            }
            *(v4h*)(orow) = w0;
            *(v4h*)(orow + 16) = w1;
        }
    }
}

// ---------------- proj GEMM (128x128, 2-phase dbuf pipeline, XCD swizzle) ----------------
__global__ __launch_bounds__(256) void proj_gemm(
    const f16* __restrict__ ao, const f16* __restrict__ pwt,
    const float* __restrict__ pb, float* __restrict__ out) {
    __shared__ f16 ABs[16384];
    const int lin = blockIdx.x;
    const int m0 = ((lin / 24) * 8 + (lin & 7)) * 128;
    const int n0 = ((lin >> 3) % 3) * 128;
    const int tid = threadIdx.x;
    const int wave = tid >> 6, lane = tid & 63;
    const int quad = lane >> 4, l15 = lane & 15;
    const int wm = (wave >> 1) * 64, wn = (wave & 1) * 64;
    const int srow = lane >> 2, scol = (lane & 3) * 8;
    const f16* ga0 = ao + (size_t)(m0 + wave * 32 + srow) * DIMD + scol;
    const f16* ga1 = ga0 + (size_t)16 * DIMD;
    const f16* gb0 = pwt + (size_t)(n0 + wave * 32 + srow) * DIMD + scol;
    const f16* gb1 = gb0 + (size_t)16 * DIMD;
    {
        f16* la = ABs + wave * 1024;
        async_cp16(ga0, la);
        async_cp16(ga1, la + 512);
        async_cp16(gb0, la + 4096);
        async_cp16(gb1, la + 4096 + 512);
    }
    __syncthreads();
    v4f acc[4][4] = {};
    for (int t = 0; t < 12; ++t) {
        const int cur = (t & 1) << 13;
        if (t < 11) {
            const int nk = (t + 1) * 32;
            f16* la = ABs + (cur ^ 8192) + wave * 1024;
            async_cp16(ga0 + nk, la);
            async_cp16(ga1 + nk, la + 512);
            async_cp16(gb0 + nk, la + 4096);
            async_cp16(gb1 + nk, la + 4096 + 512);
        }
        const f16* As = ABs + cur;
        const f16* Bs = As + 4096;
        v8h a[4], b[4];
#pragma unroll
        for (int i = 0; i < 4; ++i) a[i] = *(const v8h*)(As + (wm + i * 16 + l15) * 32 + quad * 8);
#pragma unroll
        for (int j = 0; j < 4; ++j) b[j] = *(const v8h*)(Bs + (wn + j * 16 + l15) * 32 + quad * 8);
#pragma unroll
        for (int i = 0; i < 4; ++i)
#pragma unroll
            for (int j = 0; j < 4; ++j)
                acc[i][j] = __builtin_amdgcn_mfma_f32_16x16x32_f16(a[i], b[j], acc[i][j], 0, 0, 0);
        __syncthreads();
    }
#pragma unroll
    for (int i = 0; i < 4; ++i)
#pragma unroll
        for (int e = 0; e < 4; ++e) {
            int gm = m0 + wm + i * 16 + quad * 4 + e;
            if (gm < NTOK) {
#pragma unroll
                for (int j = 0; j < 4; ++j) {
                    int gn = n0 + wn + j * 16 + l15;
                    out[(size_t)gm * DIMD + gn] = acc[i][j][e] + pb[gn];
                }
            }
        }
}

extern "C" void kernel_launch(void* const* d_in, const int* in_sizes, int n_in,
                              void* d_out, int out_size, void* d_ws, size_t ws_size,
                              hipStream_t stream) {
    const float* x      = (const float*)d_in[0];
    const float* qkv_w  = (const float*)d_in[1];
    const float* table  = (const float*)d_in[2];
    const float* proj_w = (const float*)d_in[3];
    const float* proj_b = (const float*)d_in[4];
    const int* mask     = (const int*)d_in[5];
    const int* rel      = (const int*)d_in[6];
    float* out = (float*)d_out;
    char* ws = (char*)d_ws;

    f16* q    = (f16*)(ws + OFF_Q);
    f16* k    = (f16*)(ws + OFF_K);
    f16* v    = (f16*)(ws + OFF_V);
    f16* xh   = (f16*)(ws + OFF_AO);   // xh and ao share the [MP][384] buffer
    f16* ao   = (f16*)(ws + OFF_AO);
    float* bt = (float*)(ws + OFF_BT);
    f16* wt   = (f16*)(ws + OFF_WT);
    f16* pwt  = (f16*)(ws + OFF_PWT);
    unsigned int* mex = (unsigned int*)(ws + OFF_MEX);

    (void)hipFuncSetAttribute((const void*)attn_kernel,
                              hipFuncAttributeMaxDynamicSharedMemorySize, SMEM_ATTN);

    prep_all<<<(SPREP + 255) / 256, 256, 0, stream>>>(
        x, xh, qkv_w, wt, proj_w, pwt, table, rel, bt, mask, mex);
    qkv_gemm<<<dim3(MPT * 9), 256, 0, stream>>>(xh, wt, q, k, v);
    attn_kernel<<<dim3(NWW * NHH), 512, SMEM_ATTN, stream>>>(q, k, v, bt, mex, ao);
    proj_gemm<<<dim3(MPT * 3), 256, 0, stream>>>(ao, pwt, proj_b, out);
}

// Round 12
// 203.881 us; speedup vs baseline: 1.2384x; 1.2384x over previous
//
#include <hip/hip_runtime.h>

// WindowAttention (Swin-3D) on MI355X / gfx950.
// R26 = R22 verbatim (measured best: 200.4us). Consolidation after the
// R23-R25 bisect: sigma-V register-fragment path produced wrong results
// (R24), and mex halfword masks, while correct (R25), cost more in mask
// bandwidth (prep FETCH 43->212MB, attn +176B/lane/q-tile) than the VALU
// they saved (net -52us). R22 components, each measured: ILP prep (42.5->
// <41us), 2-phase dbuf GEMMs, attn = LDS-P round trip (zero scratch, VGPR
// 40) + conflict-reduced Vts [ktp][32][32] + in-register mask bitmask.

#define DIMD 384
#define NHH 12
#define HEADD 32
#define LL 343
#define NWW 64
#define NTOK (NWW * LL)            // 21952
#define MPT 176                    // m tiles (128 each)
#define MP (MPT * 128)             // 22528
#define LP 352                     // L padded to 22*16
#define QT 22
#define MW 12                      // mask words per query row (11 used)
#define SCALE_ 0.17677669529663687f
#define LOG2E_ 1.4426950408889634f
#define NEGBIG_ (-1.0e4f)

typedef _Float16 f16;
typedef _Float16 v8h __attribute__((ext_vector_type(8)));
typedef _Float16 v4h __attribute__((ext_vector_type(4)));
typedef float v4f __attribute__((ext_vector_type(4)));

__device__ __forceinline__ void async_cp16(const void* g, void* l) {
    __builtin_amdgcn_global_load_lds(
        (const __attribute__((address_space(1))) void*)g,
        (__attribute__((address_space(3))) void*)l, 16, 0, 0);
}

__device__ __forceinline__ unsigned int pk2(float a, float b) {
    return __builtin_bit_cast(unsigned int, __builtin_amdgcn_cvt_pkrtz(a, b));
}

// ---- workspace layout (bytes) ----
constexpr size_t HBUF = (size_t)NHH * MP * HEADD * 2;          // per q/k/v
constexpr size_t OFF_Q    = 0;
constexpr size_t OFF_K    = OFF_Q  + HBUF;
constexpr size_t OFF_V    = OFF_K  + HBUF;
constexpr size_t OFF_AO   = OFF_V  + HBUF;                     // f16 [MP][384]; xh then AO
constexpr size_t OFF_BT   = OFF_AO + (size_t)MP * DIMD * 2;    // f32 biasT (NH,88,352,4) *log2e, key-major
constexpr size_t OFF_WT   = OFF_BT + (size_t)NHH * LP * LP * 4;
constexpr size_t OFF_PWT  = OFF_WT + (size_t)3 * DIMD * DIMD * 2;
constexpr size_t OFF_MTB  = OFF_PWT + (size_t)DIMD * DIMD * 2; // uint (NW, 352 queries, 12 key-words)

// attn LDS: Ks [352][32] + Vts [11][32][32] + Ps 8x[16][32]
constexpr int SMEM_ATTN = (LP * 32 + LP * 32 + 8 * 16 * 32) * 2;   // 53248

// ---------------- fused prep (ILP-restructured) ----------------
// branch order: bias(S3Q) -> mask(S4) -> x-conv(S0Q) -> wt(S1) -> pwt(S2)
#define S3Q (NHH * LP * LP / 4)        // 371712 threads, 4 bias elems each
#define S4  (NWW * MW * LP)            // 270336
#define S0Q (NTOK * DIMD / 8)          // 1053696 threads, 8 f32 each
#define S1  (3 * DIMD * DIMD)          // 442368
#define S2  (DIMD * DIMD)              // 147456
#define B0  (S3Q)
#define B1  (B0 + S4)
#define B2  (B1 + S0Q)
#define B3  (B2 + S1)
#define SPREP (B3 + S2)

__global__ __launch_bounds__(256) void prep_all(
    const float* __restrict__ x, f16* __restrict__ xh,
    const float* __restrict__ qkv_w, f16* __restrict__ wt,
    const float* __restrict__ proj_w, f16* __restrict__ pwt,
    const float* __restrict__ table, const int* __restrict__ rel, float* __restrict__ btf,
    const int* __restrict__ mask, unsigned int* __restrict__ mtb) {
    int t = blockIdx.x * 256 + threadIdx.x;
    if (t < B0) {
        // biasT[h][kq][col][j] = bias(h, query=col, key=kq*4+j)*log2e, pads -> -1e4
        int h = t / (88 * LP);
        int rem = t % (88 * LP);
        int kq = rem / LP, col = rem % LP;
        int idx[4];
        const int* rrow = rel + col * LL + kq * 4;
#pragma unroll
        for (int j = 0; j < 4; ++j) {
            int key = kq * 4 + j;
            idx[j] = (col < LL && key < LL) ? rrow[j] : -1;
        }
        v4f o;
#pragma unroll
        for (int j = 0; j < 4; ++j)
            o[j] = (idx[j] >= 0) ? table[(size_t)idx[j] * NHH + h] * LOG2E_ : NEGBIG_;
        *(v4f*)(btf + ((size_t)(h * 88 + kq) * LP + col) * 4) = o;
    } else if (t < B1) {
        // mtb[n][q][kw]: bit b = mask[n][query q][key kw*32+b]; fully unrolled
        int e = t - B0;
        int n = e / (MW * LP), rem = e % (MW * LP);
        int q = rem / MW, kw = rem % MW;
        unsigned int wd = 0;
        if (q < LL && kw < 11) {
            const int* mrow = mask + ((size_t)n * LL + q) * LL + kw * 32;
            if (kw < 10) {
#pragma unroll
                for (int b = 0; b < 32; ++b) wd |= mrow[b] ? (1u << b) : 0u;
            } else {        // kw == 10: keys 320..342 -> 23 valid
#pragma unroll
                for (int b = 0; b < 23; ++b) wd |= mrow[b] ? (1u << b) : 0u;
            }
        }
        mtb[((size_t)n * LP + q) * MW + kw] = wd;
    } else if (t < B2) {
        // x -> f16, 8 elems/thread, one 16B store
        int e = t - B1;
        const float4* xp = (const float4*)x + (size_t)e * 2;
        float4 va = xp[0], vb = xp[1];
        v8h o;
        o[0] = (f16)va.x; o[1] = (f16)va.y; o[2] = (f16)va.z; o[3] = (f16)va.w;
        o[4] = (f16)vb.x; o[5] = (f16)vb.y; o[6] = (f16)vb.z; o[7] = (f16)vb.w;
        *(v8h*)(xh + (size_t)e * 8) = o;
    } else if (t < B3) {
        int e = t - B2;
        int n = e / DIMD, k = e % DIMD;          // wt[n][k] = qkv_w[k][n]
        wt[e] = (f16)qkv_w[(size_t)k * (3 * DIMD) + n];
    } else if (t < SPREP) {
        int e = t - B3;
        int n = e / DIMD, k = e % DIMD;
        pwt[e] = (f16)proj_w[(size_t)k * DIMD + n];
    }
}

// ---------------- QKV GEMM (128x128, 2-phase dbuf pipeline, XCD swizzle) ----------------
__global__ __launch_bounds__(256) void qkv_gemm(
    const f16* __restrict__ xh, const f16* __restrict__ wt,
    f16* __restrict__ qb, f16* __restrict__ kb, f16* __restrict__ vb) {
    __shared__ f16 ABs[16384];       // 2 bufs x (A 128x32 + B 128x32)
    const int lin = blockIdx.x;
    const int m0 = ((lin / 72) * 8 + (lin & 7)) * 128;
    const int n0 = ((lin >> 3) % 9) * 128;
    const int tid = threadIdx.x;
    const int wave = tid >> 6, lane = tid & 63;
    const int quad = lane >> 4, l15 = lane & 15;
    const int wm = (wave >> 1) * 64, wn = (wave & 1) * 64;
    const int srow = lane >> 2, scol = (lane & 3) * 8;
    const f16* ga0 = xh + (size_t)(m0 + wave * 32 + srow) * DIMD + scol;
    const f16* ga1 = ga0 + (size_t)16 * DIMD;
    const f16* gb0 = wt + (size_t)(n0 + wave * 32 + srow) * DIMD + scol;
    const f16* gb1 = gb0 + (size_t)16 * DIMD;
    {
        f16* la = ABs + wave * 1024;
        async_cp16(ga0, la);
        async_cp16(ga1, la + 512);
        async_cp16(gb0, la + 4096);
        async_cp16(gb1, la + 4096 + 512);
    }
    __syncthreads();
    v4f acc[4][4] = {};
    for (int t = 0; t < 12; ++t) {
        const int cur = (t & 1) << 13;          // 0 / 8192 f16 flip
        if (t < 11) {                            // prefetch next tile: overlaps MFMA below
            const int nk = (t + 1) * 32;
            f16* la = ABs + (cur ^ 8192) + wave * 1024;
            async_cp16(ga0 + nk, la);
            async_cp16(ga1 + nk, la + 512);
            async_cp16(gb0 + nk, la + 4096);
            async_cp16(gb1 + nk, la + 4096 + 512);
        }
        const f16* As = ABs + cur;
        const f16* Bs = As + 4096;
        v8h a[4], b[4];
#pragma unroll
        for (int i = 0; i < 4; ++i) a[i] = *(const v8h*)(As + (wm + i * 16 + l15) * 32 + quad * 8);
#pragma unroll
        for (int j = 0; j < 4; ++j) b[j] = *(const v8h*)(Bs + (wn + j * 16 + l15) * 32 + quad * 8);
#pragma unroll
        for (int i = 0; i < 4; ++i)
#pragma unroll
            for (int j = 0; j < 4; ++j)
                acc[i][j] = __builtin_amdgcn_mfma_f32_16x16x32_f16(a[i], b[j], acc[i][j], 0, 0, 0);
        __syncthreads();                         // single barrier: drains prefetch (vmcnt0) + protects buf reuse
    }
    // epilogue: per-wave private LDS transpose, zero barriers, coalesced 16B stores
    const int t3 = n0 / DIMD;
    f16* dst = (t3 == 0) ? qb : (t3 == 1) ? kb : vb;
    const float sc = (t3 == 0) ? (SCALE_ * LOG2E_) : 1.0f;
    const int nrel = n0 - t3 * DIMD;
    f16* Cw = ABs + wave * (16 * 72);            // [16 rows][72 stride], wave-private
#pragma unroll
    for (int i = 0; i < 4; ++i) {
#pragma unroll
        for (int e = 0; e < 4; ++e)
#pragma unroll
            for (int j = 0; j < 4; ++j)
                Cw[(quad * 4 + e) * 72 + j * 16 + l15] = (f16)(acc[i][j][e] * sc);
        // same-wave DS ordering: no barrier needed
#pragma unroll
        for (int c = 0; c < 2; ++c) {
            int chunk = quad + c * 4;            // 0..7 -> 8-col piece
            int gm = m0 + wm + i * 16 + l15;
            int gcol = nrel + wn + chunk * 8;
            if (gm < NTOK) {
                size_t off = (size_t)(gcol >> 5) * ((size_t)MP * HEADD)
                           + (gcol & 31) + (size_t)gm * HEADD;
                *(v8h*)(dst + off) = *(const v8h*)(Cw + l15 * 72 + chunk * 8);
            }
        }
    }
}

// ---------------- attention (S^T tiles, reg-mask, LDS-P, new Vts, 3 blk/CU) ----------------
__global__ __launch_bounds__(512, 6) void attn_kernel(
    const f16* __restrict__ qb, const f16* __restrict__ kb, const f16* __restrict__ vb,
    const float* __restrict__ biasT, const unsigned int* __restrict__ mtb,
    f16* __restrict__ ao) {
    extern __shared__ char smem[];
    f16* Ks  = (f16*)smem;            // [352 keys][32 ch], 16B-block XOR by (key&3)
    f16* Vts = Ks + LP * 32;          // [11 ktp][32 ch][32 keys], key-block XOR by (ch>>3)&3
    f16* Ps  = Vts + LP * 32;         // 8 waves x [16 q][32 keys], block XOR by ((l15>>1)&3)
    const int bid = blockIdx.x;
    // XCD-chunked swizzle: XCD x owns j2 in [96x, 96x+96) -> 1.5 head slices per XCD L2
    const int j2 = (bid & 7) * 96 + (bid >> 3);
    const int n = j2 & 63, h = j2 >> 6;
    const int tid = threadIdx.x, wave = tid >> 6, lane = tid & 63;
    const int quad = lane >> 4, l15 = lane & 15;
    const size_t slice = ((size_t)h * MP + n * LL) * HEADD;
    const f16* qg = qb + slice;
    const f16* kg = kb + slice;
    const f16* vg = vb + slice;
    // K staging: [key][32ch], swizzled 16B blocks, zero-pad keys >= LL
    for (int i = tid; i < LP * 4; i += 512) {
        int row = i >> 2, c8 = i & 3;
        v8h vv = {};
        if (row < LL) vv = *(const v8h*)(kg + (size_t)i * 8);
        *(v8h*)(Ks + row * 32 + ((c8 ^ (row & 3)) << 3)) = vv;
    }
    // V^T staging: [ktp][ch][key32], key-block XOR by (ch>>3)&3
    for (int i = tid; i < LP * 4; i += 512) {
        int key = i >> 2, c8 = i & 3;
        v8h vv = {};
        if (key < LL) vv = *(const v8h*)(vg + (size_t)key * HEADD + c8 * 8);
        int kk = key & 31;
        f16* d = Vts + (key >> 5) * 1024 + ((((kk >> 3) ^ c8) & 3) << 3) + (kk & 7);
#pragma unroll
        for (int j = 0; j < 8; ++j) d[(c8 * 8 + j) * 32] = vv[j];
    }
    __syncthreads();
    f16* Pw = Ps + wave * (16 * 32);
    const float* bh = biasT + (size_t)h * LP * LP;     // [88 key-quads][352 q][4]
    const unsigned int* mg = mtb + (size_t)n * LP * MW;
    const v8h ones = {(f16)1.f, (f16)1.f, (f16)1.f, (f16)1.f,
                      (f16)1.f, (f16)1.f, (f16)1.f, (f16)1.f};
    const int pswz = (l15 >> 1) & 3;
    const int kswz = (quad ^ (l15 & 3)) << 3;
    const int xw = (l15 >> 3) & 1;
    for (int qt = wave; qt < QT; qt += 8) {
        const int q = qt * 16 + l15;
        v8h af = *(const v8h*)(qg + (size_t)q * HEADD + quad * 8);      // Q[q][ch]
        uint4 mA = *(const uint4*)(mg + q * MW);
        uint4 mB = *(const uint4*)(mg + q * MW + 4);
        uint4 mC = *(const uint4*)(mg + q * MW + 8);
        unsigned int m[12] = {mA.x, mA.y, mA.z, mA.w, mB.x, mB.y, mB.z, mB.w,
                              mC.x, mC.y, mC.z, mC.w};
        const float* bq = bh + (size_t)q * 4;
        v4f cinN[2];
        cinN[0] = *(const v4f*)(bq + (size_t)(quad) * (LP * 4));
        cinN[1] = *(const v4f*)(bq + (size_t)(4 + quad) * (LP * 4));
        v4f o0 = {}, o1 = {}, o2 = {};
#pragma unroll
        for (int ktp = 0; ktp < 11; ++ktp) {
            v4f cin0 = cinN[0], cin1 = cinN[1];
            if (ktp < 10) {   // depth-1 prefetch: overlaps this tile's exp/PV
                cinN[0] = *(const v4f*)(bq + (size_t)((ktp + 1) * 8 + quad) * (LP * 4));
                cinN[1] = *(const v4f*)(bq + (size_t)((ktp + 1) * 8 + 4 + quad) * (LP * 4));
            }
            v8h bf0 = *(const v8h*)(Ks + (ktp * 32 + l15) * 32 + kswz);
            v8h bf1 = *(const v8h*)(Ks + (ktp * 32 + 16 + l15) * 32 + kswz);
            unsigned int mw = m[ktp];
            unsigned int mb0 = mw >> (quad * 4);
            unsigned int mb1 = mw >> (quad * 4 + 16);
#pragma unroll
            for (int e = 0; e < 4; ++e) {
                if ((mb0 >> e) & 1u) cin0[e] = NEGBIG_;
                if ((mb1 >> e) & 1u) cin1[e] = NEGBIG_;
            }
            // S^T tile: rows = keys (quad*4+e), cols = queries (l15)
            v4f s0 = __builtin_amdgcn_mfma_f32_16x16x32_f16(bf0, af, cin0, 0, 0, 0);
            v4f s1 = __builtin_amdgcn_mfma_f32_16x16x32_f16(bf1, af, cin1, 0, 0, 0);
            unsigned int u0 = pk2(__builtin_amdgcn_exp2f(s0[0]), __builtin_amdgcn_exp2f(s0[1]));
            unsigned int u1 = pk2(__builtin_amdgcn_exp2f(s0[2]), __builtin_amdgcn_exp2f(s0[3]));
            unsigned int u2 = pk2(__builtin_amdgcn_exp2f(s1[0]), __builtin_amdgcn_exp2f(s1[1]));
            unsigned int u3 = pk2(__builtin_amdgcn_exp2f(s1[2]), __builtin_amdgcn_exp2f(s1[3]));
            // P[q=l15][key 0..31]: logical block b = half*2 + (quad>>1), XOR pswz
            // b64 stores: 8B contiguous (keys quad*4..+3), bank-uniform (4 dw/bank)
            f16* pr = Pw + l15 * 32 + (quad & 1) * 4;
            *(uint2*)(pr + ((((quad >> 1) + 0) ^ pswz) << 3)) = make_uint2(u0, u1);
            *(uint2*)(pr + ((((quad >> 1) + 2) ^ pswz) << 3)) = make_uint2(u2, u3);
            v8h a = *(const v8h*)(Pw + l15 * 32 + ((quad ^ pswz) << 3));
            const f16* vt = Vts + ktp * 1024;
            v8h w0 = *(const v8h*)(vt + l15 * 32 + ((quad ^ xw) << 3));            // ch 0..15
            v8h w1 = *(const v8h*)(vt + (16 + l15) * 32 + ((quad ^ 2 ^ xw) << 3)); // ch 16..31
            // O^T: rows = ch (quad*4+e), cols = queries (l15)
            o0 = __builtin_amdgcn_mfma_f32_16x16x32_f16(w0, a, o0, 0, 0, 0);
            o1 = __builtin_amdgcn_mfma_f32_16x16x32_f16(w1, a, o1, 0, 0, 0);
            o2 = __builtin_amdgcn_mfma_f32_16x16x32_f16(ones, a, o2, 0, 0, 0);  // rsum[q]
        }
        if (q < LL) {
            float inv = 1.0f / o2[0];          // rsum for this lane's query, uniform in e
            f16* orow = ao + ((size_t)(n * LL + q)) * DIMD + h * HEADD + quad * 4;
            v4h w0, w1;
#pragma unroll
            for (int e = 0; e < 4; ++e) {
                w0[e] = (f16)(o0[e] * inv);
                w1[e] = (f16)(o1[e] * inv);
            }
            *(v4h*)(orow) = w0;
            *(v4h*)(orow + 16) = w1;
        }
    }
}

// ---------------- proj GEMM (128x128, 2-phase dbuf pipeline, XCD swizzle) ----------------
__global__ __launch_bounds__(256) void proj_gemm(
    const f16* __restrict__ ao, const f16* __restrict__ pwt,
    const float* __restrict__ pb, float* __restrict__ out) {
    __shared__ f16 ABs[16384];
    const int lin = blockIdx.x;
    const int m0 = ((lin / 24) * 8 + (lin & 7)) * 128;
    const int n0 = ((lin >> 3) % 3) * 128;
    const int tid = threadIdx.x;
    const int wave = tid >> 6, lane = tid & 63;
    const int quad = lane >> 4, l15 = lane & 15;
    const int wm = (wave >> 1) * 64, wn = (wave & 1) * 64;
    const int srow = lane >> 2, scol = (lane & 3) * 8;
    const f16* ga0 = ao + (size_t)(m0 + wave * 32 + srow) * DIMD + scol;
    const f16* ga1 = ga0 + (size_t)16 * DIMD;
    const f16* gb0 = pwt + (size_t)(n0 + wave * 32 + srow) * DIMD + scol;
    const f16* gb1 = gb0 + (size_t)16 * DIMD;
    {
        f16* la = ABs + wave * 1024;
        async_cp16(ga0, la);
        async_cp16(ga1, la + 512);
        async_cp16(gb0, la + 4096);
        async_cp16(gb1, la + 4096 + 512);
    }
    __syncthreads();
    v4f acc[4][4] = {};
    for (int t = 0; t < 12; ++t) {
        const int cur = (t & 1) << 13;
        if (t < 11) {
            const int nk = (t + 1) * 32;
            f16* la = ABs + (cur ^ 8192) + wave * 1024;
            async_cp16(ga0 + nk, la);
            async_cp16(ga1 + nk, la + 512);
            async_cp16(gb0 + nk, la + 4096);
            async_cp16(gb1 + nk, la + 4096 + 512);
        }
        const f16* As = ABs + cur;
        const f16* Bs = As + 4096;
        v8h a[4], b[4];
#pragma unroll
        for (int i = 0; i < 4; ++i) a[i] = *(const v8h*)(As + (wm + i * 16 + l15) * 32 + quad * 8);
#pragma unroll
        for (int j = 0; j < 4; ++j) b[j] = *(const v8h*)(Bs + (wn + j * 16 + l15) * 32 + quad * 8);
#pragma unroll
        for (int i = 0; i < 4; ++i)
#pragma unroll
            for (int j = 0; j < 4; ++j)
                acc[i][j] = __builtin_amdgcn_mfma_f32_16x16x32_f16(a[i], b[j], acc[i][j], 0, 0, 0);
        __syncthreads();
    }
#pragma unroll
    for (int i = 0; i < 4; ++i)
#pragma unroll
        for (int e = 0; e < 4; ++e) {
            int gm = m0 + wm + i * 16 + quad * 4 + e;
            if (gm < NTOK) {
#pragma unroll
                for (int j = 0; j < 4; ++j) {
                    int gn = n0 + wn + j * 16 + l15;
                    out[(size_t)gm * DIMD + gn] = acc[i][j][e] + pb[gn];
                }
            }
        }
}

extern "C" void kernel_launch(void* const* d_in, const int* in_sizes, int n_in,
                              void* d_out, int out_size, void* d_ws, size_t ws_size,
                              hipStream_t stream) {
    const float* x      = (const float*)d_in[0];
    const float* qkv_w  = (const float*)d_in[1];
    const float* table  = (const float*)d_in[2];
    const float* proj_w = (const float*)d_in[3];
    const float* proj_b = (const float*)d_in[4];
    const int* mask     = (const int*)d_in[5];
    const int* rel      = (const int*)d_in[6];
    float* out = (float*)d_out;
    char* ws = (char*)d_ws;

    f16* q    = (f16*)(ws + OFF_Q);
    f16* k    = (f16*)(ws + OFF_K);
    f16* v    = (f16*)(ws + OFF_V);
    f16* xh   = (f16*)(ws + OFF_AO);   // xh and ao share the [MP][384] buffer
    f16* ao   = (f16*)(ws + OFF_AO);
    float* bt = (float*)(ws + OFF_BT);
    f16* wt   = (f16*)(ws + OFF_WT);
    f16* pwt  = (f16*)(ws + OFF_PWT);
    unsigned int* mtb = (unsigned int*)(ws + OFF_MTB);

    (void)hipFuncSetAttribute((const void*)attn_kernel,
                              hipFuncAttributeMaxDynamicSharedMemorySize, SMEM_ATTN);

    prep_all<<<(SPREP + 255) / 256, 256, 0, stream>>>(
        x, xh, qkv_w, wt, proj_w, pwt, table, rel, bt, mask, mtb);
    qkv_gemm<<<dim3(MPT * 9), 256, 0, stream>>>(xh, wt, q, k, v);
    attn_kernel<<<dim3(NWW * NHH), 512, SMEM_ATTN, stream>>>(q, k, v, bt, mtb, ao);
    proj_gemm<<<dim3(MPT * 3), 256, 0, stream>>>(ao, pwt, proj_b, out);
}

// Round 14
// 193.502 us; speedup vs baseline: 1.3048x; 1.0536x over previous
//
#include <hip/hip_runtime.h>

// WindowAttention (Swin-3D) on MI355X / gfx950.
// R28 = R26 (passing, ~200-204us) + ONE change: prep bias branch inverted
// (one thread per (kq,col) computes all 12 heads: 4 rel loads reused 12x,
// 12x float4 table-row loads, 12 coalesced v4f stores). The R27 failure is
// attributed to the pair-packed u32 V-staging skeleton (identical absmax in
// R23/R24/R27, all sharing that loop; R23/R24 did NOT have this bias
// change) -- so V staging here stays the R26 scalar form, byte-for-byte.

#define DIMD 384
#define NHH 12
#define HEADD 32
#define LL 343
#define NWW 64
#define NTOK (NWW * LL)            // 21952
#define MPT 176                    // m tiles (128 each)
#define MP (MPT * 128)             // 22528
#define LP 352                     // L padded to 22*16
#define QT 22
#define MW 12                      // mask words per query row (11 used)
#define SCALE_ 0.17677669529663687f
#define LOG2E_ 1.4426950408889634f
#define NEGBIG_ (-1.0e4f)

typedef _Float16 f16;
typedef _Float16 v8h __attribute__((ext_vector_type(8)));
typedef _Float16 v4h __attribute__((ext_vector_type(4)));
typedef float v4f __attribute__((ext_vector_type(4)));

__device__ __forceinline__ void async_cp16(const void* g, void* l) {
    __builtin_amdgcn_global_load_lds(
        (const __attribute__((address_space(1))) void*)g,
        (__attribute__((address_space(3))) void*)l, 16, 0, 0);
}

__device__ __forceinline__ unsigned int pk2(float a, float b) {
    return __builtin_bit_cast(unsigned int, __builtin_amdgcn_cvt_pkrtz(a, b));
}

// ---- workspace layout (bytes) ----
constexpr size_t HBUF = (size_t)NHH * MP * HEADD * 2;          // per q/k/v
constexpr size_t OFF_Q    = 0;
constexpr size_t OFF_K    = OFF_Q  + HBUF;
constexpr size_t OFF_V    = OFF_K  + HBUF;
constexpr size_t OFF_AO   = OFF_V  + HBUF;                     // f16 [MP][384]; xh then AO
constexpr size_t OFF_BT   = OFF_AO + (size_t)MP * DIMD * 2;    // f32 biasT (NH,88,352,4) *log2e, key-major
constexpr size_t OFF_WT   = OFF_BT + (size_t)NHH * LP * LP * 4;
constexpr size_t OFF_PWT  = OFF_WT + (size_t)3 * DIMD * DIMD * 2;
constexpr size_t OFF_MTB  = OFF_PWT + (size_t)DIMD * DIMD * 2; // uint (NW, 352 queries, 12 key-words)

// attn LDS: Ks [352][32] + Vts [11][32][32] + Ps 8x[16][32]
constexpr int SMEM_ATTN = (LP * 32 + LP * 32 + 8 * 16 * 32) * 2;   // 53248

// ---------------- fused prep (ILP-restructured; bias = all-heads/thread) ----------------
// branch order: bias(S3N) -> mask(S4) -> x-conv(S0Q) -> wt(S1) -> pwt(S2)
#define S3N (88 * LP)                  // 30976 threads, 4 keys x 12 heads each
#define S4  (NWW * MW * LP)            // 270336
#define S0Q (NTOK * DIMD / 8)          // 1053696 threads, 8 f32 each
#define S1  (3 * DIMD * DIMD)          // 442368
#define S2  (DIMD * DIMD)              // 147456
#define B0  (S3N)
#define B1  (B0 + S4)
#define B2  (B1 + S0Q)
#define B3  (B2 + S1)
#define SPREP (B3 + S2)

__global__ __launch_bounds__(256) void prep_all(
    const float* __restrict__ x, f16* __restrict__ xh,
    const float* __restrict__ qkv_w, f16* __restrict__ wt,
    const float* __restrict__ proj_w, f16* __restrict__ pwt,
    const float* __restrict__ table, const int* __restrict__ rel, float* __restrict__ btf,
    const int* __restrict__ mask, unsigned int* __restrict__ mtb) {
    int t = blockIdx.x * 256 + threadIdx.x;
    if (t < B0) {
        // biasT[h][kq][col][j] = bias(h, query=col, key=kq*4+j)*log2e, pads -> -1e4
        // one thread per (kq,col): 4 rel loads, 12 float4 table-row loads
        // (16B-aligned: idx*48B + c*16B), 12 coalesced v4f stores.
        int kq = t / LP, col = t % LP;
        int idx[4];
        const int* rrow = rel + col * LL + kq * 4;
#pragma unroll
        for (int j = 0; j < 4; ++j) {
            int key = kq * 4 + j;
            idx[j] = (col < LL && key < LL) ? rrow[j] : -1;
        }
        v4f tr[4][3];
#pragma unroll
        for (int j = 0; j < 4; ++j) {
            const float* tp = table + (size_t)(idx[j] < 0 ? 0 : idx[j]) * NHH;
#pragma unroll
            for (int c = 0; c < 3; ++c) tr[j][c] = *(const v4f*)(tp + c * 4);
        }
#pragma unroll
        for (int h = 0; h < NHH; ++h) {
            v4f o;
#pragma unroll
            for (int j = 0; j < 4; ++j)
                o[j] = (idx[j] >= 0) ? tr[j][h >> 2][h & 3] * LOG2E_ : NEGBIG_;
            *(v4f*)(btf + ((size_t)(h * 88 + kq) * LP + col) * 4) = o;
        }
    } else if (t < B1) {
        // mtb[n][q][kw]: bit b = mask[n][query q][key kw*32+b]; fully unrolled
        int e = t - B0;
        int n = e / (MW * LP), rem = e % (MW * LP);
        int q = rem / MW, kw = rem % MW;
        unsigned int wd = 0;
        if (q < LL && kw < 11) {
            const int* mrow = mask + ((size_t)n * LL + q) * LL + kw * 32;
            if (kw < 10) {
#pragma unroll
                for (int b = 0; b < 32; ++b) wd |= mrow[b] ? (1u << b) : 0u;
            } else {        // kw == 10: keys 320..342 -> 23 valid
#pragma unroll
                for (int b = 0; b < 23; ++b) wd |= mrow[b] ? (1u << b) : 0u;
            }
        }
        mtb[((size_t)n * LP + q) * MW + kw] = wd;
    } else if (t < B2) {
        // x -> f16, 8 elems/thread, one 16B store
        int e = t - B1;
        const float4* xp = (const float4*)x + (size_t)e * 2;
        float4 va = xp[0], vb = xp[1];
        v8h o;
        o[0] = (f16)va.x; o[1] = (f16)va.y; o[2] = (f16)va.z; o[3] = (f16)va.w;
        o[4] = (f16)vb.x; o[5] = (f16)vb.y; o[6] = (f16)vb.z; o[7] = (f16)vb.w;
        *(v8h*)(xh + (size_t)e * 8) = o;
    } else if (t < B3) {
        int e = t - B2;
        int n = e / DIMD, k = e % DIMD;          // wt[n][k] = qkv_w[k][n]
        wt[e] = (f16)qkv_w[(size_t)k * (3 * DIMD) + n];
    } else if (t < SPREP) {
        int e = t - B3;
        int n = e / DIMD, k = e % DIMD;
        pwt[e] = (f16)proj_w[(size_t)k * DIMD + n];
    }
}

// ---------------- QKV GEMM (128x128, 2-phase dbuf pipeline, XCD swizzle) ----------------
__global__ __launch_bounds__(256) void qkv_gemm(
    const f16* __restrict__ xh, const f16* __restrict__ wt,
    f16* __restrict__ qb, f16* __restrict__ kb, f16* __restrict__ vb) {
    __shared__ f16 ABs[16384];       // 2 bufs x (A 128x32 + B 128x32)
    const int lin = blockIdx.x;
    const int m0 = ((lin / 72) * 8 + (lin & 7)) * 128;
    const int n0 = ((lin >> 3) % 9) * 128;
    const int tid = threadIdx.x;
    const int wave = tid >> 6, lane = tid & 63;
    const int quad = lane >> 4, l15 = lane & 15;
    const int wm = (wave >> 1) * 64, wn = (wave & 1) * 64;
    const int srow = lane >> 2, scol = (lane & 3) * 8;
    const f16* ga0 = xh + (size_t)(m0 + wave * 32 + srow) * DIMD + scol;
    const f16* ga1 = ga0 + (size_t)16 * DIMD;
    const f16* gb0 = wt + (size_t)(n0 + wave * 32 + srow) * DIMD + scol;
    const f16* gb1 = gb0 + (size_t)16 * DIMD;
    {
        f16* la = ABs + wave * 1024;
        async_cp16(ga0, la);
        async_cp16(ga1, la + 512);
        async_cp16(gb0, la + 4096);
        async_cp16(gb1, la + 4096 + 512);
    }
    __syncthreads();
    v4f acc[4][4] = {};
    for (int t = 0; t < 12; ++t) {
        const int cur = (t & 1) << 13;          // 0 / 8192 f16 flip
        if (t < 11) {                            // prefetch next tile: overlaps MFMA below
            const int nk = (t + 1) * 32;
            f16* la = ABs + (cur ^ 8192) + wave * 1024;
            async_cp16(ga0 + nk, la);
            async_cp16(ga1 + nk, la + 512);
            async_cp16(gb0 + nk, la + 4096);
            async_cp16(gb1 + nk, la + 4096 + 512);
        }
        const f16* As = ABs + cur;
        const f16* Bs = As + 4096;
        v8h a[4], b[4];
#pragma unroll
        for (int i = 0; i < 4; ++i) a[i] = *(const v8h*)(As + (wm + i * 16 + l15) * 32 + quad * 8);
#pragma unroll
        for (int j = 0; j < 4; ++j) b[j] = *(const v8h*)(Bs + (wn + j * 16 + l15) * 32 + quad * 8);
#pragma unroll
        for (int i = 0; i < 4; ++i)
#pragma unroll
            for (int j = 0; j < 4; ++j)
                acc[i][j] = __builtin_amdgcn_mfma_f32_16x16x32_f16(a[i], b[j], acc[i][j], 0, 0, 0);
        __syncthreads();                         // single barrier: drains prefetch (vmcnt0) + protects buf reuse
    }
    // epilogue: per-wave private LDS transpose, zero barriers, coalesced 16B stores
    const int t3 = n0 / DIMD;
    f16* dst = (t3 == 0) ? qb : (t3 == 1) ? kb : vb;
    const float sc = (t3 == 0) ? (SCALE_ * LOG2E_) : 1.0f;
    const int nrel = n0 - t3 * DIMD;
    f16* Cw = ABs + wave * (16 * 72);            // [16 rows][72 stride], wave-private
#pragma unroll
    for (int i = 0; i < 4; ++i) {
#pragma unroll
        for (int e = 0; e < 4; ++e)
#pragma unroll
            for (int j = 0; j < 4; ++j)
                Cw[(quad * 4 + e) * 72 + j * 16 + l15] = (f16)(acc[i][j][e] * sc);
        // same-wave DS ordering: no barrier needed
#pragma unroll
        for (int c = 0; c < 2; ++c) {
            int chunk = quad + c * 4;            // 0..7 -> 8-col piece
            int gm = m0 + wm + i * 16 + l15;
            int gcol = nrel + wn + chunk * 8;
            if (gm < NTOK) {
                size_t off = (size_t)(gcol >> 5) * ((size_t)MP * HEADD)
                           + (gcol & 31) + (size_t)gm * HEADD;
                *(v8h*)(dst + off) = *(const v8h*)(Cw + l15 * 72 + chunk * 8);
            }
        }
    }
}

// ---------------- attention (S^T tiles, reg-mask, LDS-P, scalar V-staging) ----------------
__global__ __launch_bounds__(512, 6) void attn_kernel(
    const f16* __restrict__ qb, const f16* __restrict__ kb, const f16* __restrict__ vb,
    const float* __restrict__ biasT, const unsigned int* __restrict__ mtb,
    f16* __restrict__ ao) {
    extern __shared__ char smem[];
    f16* Ks  = (f16*)smem;            // [352 keys][32 ch], 16B-block XOR by (key&3)
    f16* Vts = Ks + LP * 32;          // [11 ktp][32 ch][32 keys], key-block XOR by (ch>>3)&3
    f16* Ps  = Vts + LP * 32;         // 8 waves x [16 q][32 keys], block XOR by ((l15>>1)&3)
    const int bid = blockIdx.x;
    // XCD-chunked swizzle: XCD x owns j2 in [96x, 96x+96) -> 1.5 head slices per XCD L2
    const int j2 = (bid & 7) * 96 + (bid >> 3);
    const int n = j2 & 63, h = j2 >> 6;
    const int tid = threadIdx.x, wave = tid >> 6, lane = tid & 63;
    const int quad = lane >> 4, l15 = lane & 15;
    const size_t slice = ((size_t)h * MP + n * LL) * HEADD;
    const f16* qg = qb + slice;
    const f16* kg = kb + slice;
    const f16* vg = vb + slice;
    // K staging: [key][32ch], swizzled 16B blocks, zero-pad keys >= LL
    for (int i = tid; i < LP * 4; i += 512) {
        int row = i >> 2, c8 = i & 3;
        v8h vv = {};
        if (row < LL) vv = *(const v8h*)(kg + (size_t)i * 8);
        *(v8h*)(Ks + row * 32 + ((c8 ^ (row & 3)) << 3)) = vv;
    }
    // V^T staging: [ktp][ch][key32], key-block XOR by (ch>>3)&3 (scalar stores;
    // the pair-packed u32 variant is empirically condemned: R23/R24/R27)
    for (int i = tid; i < LP * 4; i += 512) {
        int key = i >> 2, c8 = i & 3;
        v8h vv = {};
        if (key < LL) vv = *(const v8h*)(vg + (size_t)key * HEADD + c8 * 8);
        int kk = key & 31;
        f16* d = Vts + (key >> 5) * 1024 + ((((kk >> 3) ^ c8) & 3) << 3) + (kk & 7);
#pragma unroll
        for (int j = 0; j < 8; ++j) d[(c8 * 8 + j) * 32] = vv[j];
    }
    __syncthreads();
    f16* Pw = Ps + wave * (16 * 32);
    const float* bh = biasT + (size_t)h * LP * LP;     // [88 key-quads][352 q][4]
    const unsigned int* mg = mtb + (size_t)n * LP * MW;
    const v8h ones = {(f16)1.f, (f16)1.f, (f16)1.f, (f16)1.f,
                      (f16)1.f, (f16)1.f, (f16)1.f, (f16)1.f};
    const int pswz = (l15 >> 1) & 3;
    const int kswz = (quad ^ (l15 & 3)) << 3;
    const int xw = (l15 >> 3) & 1;
    for (int qt = wave; qt < QT; qt += 8) {
        const int q = qt * 16 + l15;
        v8h af = *(const v8h*)(qg + (size_t)q * HEADD + quad * 8);      // Q[q][ch]
        uint4 mA = *(const uint4*)(mg + q * MW);
        uint4 mB = *(const uint4*)(mg + q * MW + 4);
        uint4 mC = *(const uint4*)(mg + q * MW + 8);
        unsigned int m[12] = {mA.x, mA.y, mA.z, mA.w, mB.x, mB.y, mB.z, mB.w,
                              mC.x, mC.y, mC.z, mC.w};
        const float* bq = bh + (size_t)q * 4;
        v4f cinN[2];
        cinN[0] = *(const v4f*)(bq + (size_t)(quad) * (LP * 4));
        cinN[1] = *(const v4f*)(bq + (size_t)(4 + quad) * (LP * 4));
        v4f o0 = {}, o1 = {}, o2 = {};
#pragma unroll
        for (int ktp = 0; ktp < 11; ++ktp) {
            v4f cin0 = cinN[0], cin1 = cinN[1];
            if (ktp < 10) {   // depth-1 prefetch: overlaps this tile's exp/PV
                cinN[0] = *(const v4f*)(bq + (size_t)((ktp + 1) * 8 + quad) * (LP * 4));
                cinN[1] = *(const v4f*)(bq + (size_t)((ktp + 1) * 8 + 4 + quad) * (LP * 4));
            }
            v8h bf0 = *(const v8h*)(Ks + (ktp * 32 + l15) * 32 + kswz);
            v8h bf1 = *(const v8h*)(Ks + (ktp * 32 + 16 + l15) * 32 + kswz);
            unsigned int mw = m[ktp];
            unsigned int mb0 = mw >> (quad * 4);
            unsigned int mb1 = mw >> (quad * 4 + 16);
#pragma unroll
            for (int e = 0; e < 4; ++e) {
                if ((mb0 >> e) & 1u) cin0[e] = NEGBIG_;
                if ((mb1 >> e) & 1u) cin1[e] = NEGBIG_;
            }
            // S^T tile: rows = keys (quad*4+e), cols = queries (l15)
            v4f s0 = __builtin_amdgcn_mfma_f32_16x16x32_f16(bf0, af, cin0, 0, 0, 0);
            v4f s1 = __builtin_amdgcn_mfma_f32_16x16x32_f16(bf1, af, cin1, 0, 0, 0);
            unsigned int u0 = pk2(__builtin_amdgcn_exp2f(s0[0]), __builtin_amdgcn_exp2f(s0[1]));
            unsigned int u1 = pk2(__builtin_amdgcn_exp2f(s0[2]), __builtin_amdgcn_exp2f(s0[3]));
            unsigned int u2 = pk2(__builtin_amdgcn_exp2f(s1[0]), __builtin_amdgcn_exp2f(s1[1]));
            unsigned int u3 = pk2(__builtin_amdgcn_exp2f(s1[2]), __builtin_amdgcn_exp2f(s1[3]));
            // P[q=l15][key 0..31]: logical block b = half*2 + (quad>>1), XOR pswz
            // b64 stores: 8B contiguous (keys quad*4..+3), bank-uniform (4 dw/bank)
            f16* pr = Pw + l15 * 32 + (quad & 1) * 4;
            *(uint2*)(pr + ((((quad >> 1) + 0) ^ pswz) << 3)) = make_uint2(u0, u1);
            *(uint2*)(pr + ((((quad >> 1) + 2) ^ pswz) << 3)) = make_uint2(u2, u3);
            v8h a = *(const v8h*)(Pw + l15 * 32 + ((quad ^ pswz) << 3));
            const f16* vt = Vts + ktp * 1024;
            v8h w0 = *(const v8h*)(vt + l15 * 32 + ((quad ^ xw) << 3));            // ch 0..15
            v8h w1 = *(const v8h*)(vt + (16 + l15) * 32 + ((quad ^ 2 ^ xw) << 3)); // ch 16..31
            // O^T: rows = ch (quad*4+e), cols = queries (l15)
            o0 = __builtin_amdgcn_mfma_f32_16x16x32_f16(w0, a, o0, 0, 0, 0);
            o1 = __builtin_amdgcn_mfma_f32_16x16x32_f16(w1, a, o1, 0, 0, 0);
            o2 = __builtin_amdgcn_mfma_f32_16x16x32_f16(ones, a, o2, 0, 0, 0);  // rsum[q]
        }
        if (q < LL) {
            float inv = 1.0f / o2[0];          // rsum for this lane's query, uniform in e
            f16* orow = ao + ((size_t)(n * LL + q)) * DIMD + h * HEADD + quad * 4;
            v4h w0, w1;
#pragma unroll
            for (int e = 0; e < 4; ++e) {
                w0[e] = (f16)(o0[e] * inv);
                w1[e] = (f16)(o1[e] * inv);
            }
            *(v4h*)(orow) = w0;
            *(v4h*)(orow + 16) = w1;
        }
    }
}

// ---------------- proj GEMM (128x128, 2-phase dbuf pipeline, XCD swizzle) ----------------
__global__ __launch_bounds__(256) void proj_gemm(
    const f16* __restrict__ ao, const f16* __restrict__ pwt,
    const float* __restrict__ pb, float* __restrict__ out) {
    __shared__ f16 ABs[16384];
    const int lin = blockIdx.x;
    const int m0 = ((lin / 24) * 8 + (lin & 7)) * 128;
    const int n0 = ((lin >> 3) % 3) * 128;
    const int tid = threadIdx.x;
    const int wave = tid >> 6, lane = tid & 63;
    const int quad = lane >> 4, l15 = lane & 15;
    const int wm = (wave >> 1) * 64, wn = (wave & 1) * 64;
    const int srow = lane >> 2, scol = (lane & 3) * 8;
    const f16* ga0 = ao + (size_t)(m0 + wave * 32 + srow) * DIMD + scol;
    const f16* ga1 = ga0 + (size_t)16 * DIMD;
    const f16* gb0 = pwt + (size_t)(n0 + wave * 32 + srow) * DIMD + scol;
    const f16* gb1 = gb0 + (size_t)16 * DIMD;
    {
        f16* la = ABs + wave * 1024;
        async_cp16(ga0, la);
        async_cp16(ga1, la + 512);
        async_cp16(gb0, la + 4096);
        async_cp16(gb1, la + 4096 + 512);
    }
    __syncthreads();
    v4f acc[4][4] = {};
    for (int t = 0; t < 12; ++t) {
        const int cur = (t & 1) << 13;
        if (t < 11) {
            const int nk = (t + 1) * 32;
            f16* la = ABs + (cur ^ 8192) + wave * 1024;
            async_cp16(ga0 + nk, la);
            async_cp16(ga1 + nk, la + 512);
            async_cp16(gb0 + nk, la + 4096);
            async_cp16(gb1 + nk, la + 4096 + 512);
        }
        const f16* As = ABs + cur;
        const f16* Bs = As + 4096;
        v8h a[4], b[4];
#pragma unroll
        for (int i = 0; i < 4; ++i) a[i] = *(const v8h*)(As + (wm + i * 16 + l15) * 32 + quad * 8);
#pragma unroll
        for (int j = 0; j < 4; ++j) b[j] = *(const v8h*)(Bs + (wn + j * 16 + l15) * 32 + quad * 8);
#pragma unroll
        for (int i = 0; i < 4; ++i)
#pragma unroll
            for (int j = 0; j < 4; ++j)
                acc[i][j] = __builtin_amdgcn_mfma_f32_16x16x32_f16(a[i], b[j], acc[i][j], 0, 0, 0);
        __syncthreads();
    }
#pragma unroll
    for (int i = 0; i < 4; ++i)
#pragma unroll
        for (int e = 0; e < 4; ++e) {
            int gm = m0 + wm + i * 16 + quad * 4 + e;
            if (gm < NTOK) {
#pragma unroll
                for (int j = 0; j < 4; ++j) {
                    int gn = n0 + wn + j * 16 + l15;
                    out[(size_t)gm * DIMD + gn] = acc[i][j][e] + pb[gn];
                }
            }
        }
}

extern "C" void kernel_launch(void* const* d_in, const int* in_sizes, int n_in,
                              void* d_out, int out_size, void* d_ws, size_t ws_size,
                              hipStream_t stream) {
    const float* x      = (const float*)d_in[0];
    const float* qkv_w  = (const float*)d_in[1];
    const float* table  = (const float*)d_in[2];
    const float* proj_w = (const float*)d_in[3];
    const float* proj_b = (const float*)d_in[4];
    const int* mask     = (const int*)d_in[5];
    const int* rel      = (const int*)d_in[6];
    float* out = (float*)d_out;
    char* ws = (char*)d_ws;

    f16* q    = (f16*)(ws + OFF_Q);
    f16* k    = (f16*)(ws + OFF_K);
    f16* v    = (f16*)(ws + OFF_V);
    f16* xh   = (f16*)(ws + OFF_AO);   // xh and ao share the [MP][384] buffer
    f16* ao   = (f16*)(ws + OFF_AO);
    float* bt = (float*)(ws + OFF_BT);
    f16* wt   = (f16*)(ws + OFF_WT);
    f16* pwt  = (f16*)(ws + OFF_PWT);
    unsigned int* mtb = (unsigned int*)(ws + OFF_MTB);

    (void)hipFuncSetAttribute((const void*)attn_kernel,
                              hipFuncAttributeMaxDynamicSharedMemorySize, SMEM_ATTN);

    prep_all<<<(SPREP + 255) / 256, 256, 0, stream>>>(
        x, xh, qkv_w, wt, proj_w, pwt, table, rel, bt, mask, mtb);
    qkv_gemm<<<dim3(MPT * 9), 256, 0, stream>>>(xh, wt, q, k, v);
    attn_kernel<<<dim3(NWW * NHH), 512, SMEM_ATTN, stream>>>(q, k, v, bt, mtb, ao);
    proj_gemm<<<dim3(MPT * 3), 256, 0, stream>>>(ao, pwt, proj_b, out);
}